// Round 6
// baseline (506.547 us; speedup 1.0000x reference)
//
#include <hip/hip_runtime.h>

// Sparse 3D conv (Cin=1, Cout=16), stride-2 — parity-split two-pass.
//
// Geometry fact: with stride 2 and offsets d in {-1,0,1}^3, a hit (o,k)
// requires input x = 2o+d. For d in {0,1}^3 the hit is exactly input x's
// own floor-output (parity(x)=d) => those 8 "dense" planes carry one entry
// per input (~88% of M) and are per-(o,k) unique. The 19 offsets with a -1
// component are coincidence hits (~12% of M).
//
//  pass 1: dense entries -> bf16 planes g[8][np]   (plain stores, no atomics)
//  pass 2: out[o,:] = sum_p g[p][o] * W[k(p),:]    (overwrites all rows)
//  pass 3: sparse entries -> 16x f32 atomicAdd into out (exact)
//
// Round-5 decomposition: ~104us/iter is harness poison (496MB ws + 124MB out
// fills) — untouchable. This round cuts ws traffic ~3x (memset 105->31MB,
// reduce read 105->31MB) and removes ~12% of scatter RFO traffic.

typedef float vf4 __attribute__((ext_vector_type(4)));

__device__ inline unsigned short f32_to_bf16_rne(float x) {
    unsigned int u = __float_as_uint(x);
    unsigned int r = 0x7FFFu + ((u >> 16) & 1u);
    return (unsigned short)((u + r) >> 16);
}

// k = (dx+1)*9 + (dy+1)*3 + (dz+1). Dense iff all of dx,dy,dz in {0,1},
// i.e. k/9, (k/3)%3, k%3 all nonzero. Plane p = dx*4 + dy*2 + dz.
__device__ inline int dense_plane(int k) {   // returns -1 if sparse
    int a = k / 9, b = (k / 3) % 3, c = k % 3;
    if (a == 0 || b == 0 || c == 0) return -1;
    return ((a - 1) << 2) | ((b - 1) << 1) | (c - 1);
}

__global__ void __launch_bounds__(256)
scatter_dense(const float* __restrict__ feats,
              const int* __restrict__ in_idx,
              const int* __restrict__ out_idx,
              const int* __restrict__ k_idx,
              unsigned short* __restrict__ g,
              int M, int np) {
    int m = blockIdx.x * blockDim.x + threadIdx.x;
    if (m >= M) return;
    int p = dense_plane(k_idx[m]);
    if (p < 0) return;                       // sparse -> pass 3
    // (o,k) unique => plain store
    g[(size_t)p * np + out_idx[m]] = f32_to_bf16_rne(feats[in_idx[m]]);
}

__global__ void __launch_bounds__(256, 4)
reduce8(const unsigned int* __restrict__ g32,  // 8 planes as u32 (2x bf16)
        const float* __restrict__ weight,      // [27][16] f32
        float* __restrict__ out,
        int n_out, int half_np) {
    int t = blockIdx.x * blockDim.x + threadIdx.x;
    int o0 = t * 2;
    if (o0 >= n_out) return;

    unsigned int gu[8];
    #pragma unroll
    for (int p = 0; p < 8; ++p)
        gu[p] = g32[(size_t)p * half_np + t];   // coalesced per plane

    vf4 a0 = {0,0,0,0}, a1 = a0, a2 = a0, a3 = a0;
    vf4 b0 = a0, b1 = a0, b2 = a0, b3 = a0;
    // weight row indices for planes 0..7 (compile-time => s_load operands)
    const int KP[8] = {13, 14, 16, 17, 22, 23, 25, 26};
    #pragma unroll
    for (int p = 0; p < 8; ++p) {
        const vf4* w = (const vf4*)&weight[KP[p] * 16];  // wave-uniform
        vf4 w0 = w[0], w1 = w[1], w2 = w[2], w3 = w[3];
        float fa = __uint_as_float(gu[p] << 16);
        float fb = __uint_as_float(gu[p] & 0xFFFF0000u);
        a0 += fa * w0; a1 += fa * w1; a2 += fa * w2; a3 += fa * w3;
        b0 += fb * w0; b1 += fb * w1; b2 += fb * w2; b3 += fb * w3;
    }

    vf4* op = (vf4*)(out + (size_t)o0 * 16);
    op[0] = a0; op[1] = a1; op[2] = a2; op[3] = a3;   // coalesced 64B
    if (o0 + 1 < n_out) {
        op[4] = b0; op[5] = b1; op[6] = b2; op[7] = b3;
    }
}

__global__ void __launch_bounds__(256)
sparse_add(const float* __restrict__ feats,
           const float* __restrict__ weight,
           const int* __restrict__ in_idx,
           const int* __restrict__ out_idx,
           const int* __restrict__ k_idx,
           float* __restrict__ out,
           int M) {
    int m = blockIdx.x * blockDim.x + threadIdx.x;
    if (m >= M) return;
    int k = k_idx[m];
    if (dense_plane(k) >= 0) return;         // handled in pass 1/2
    float f = feats[in_idx[m]];
    float* op = out + (long long)out_idx[m] * 16;
    const float* w = &weight[k * 16];
    #pragma unroll
    for (int c = 0; c < 16; ++c)
        atomicAdd(op + c, f * w[c]);         // exact f32, few entries (~12% M)
}

// ---- fallback path (ws too small): known-correct atomic scatter ----
__global__ void __launch_bounds__(256)
sparse_conv_scatter_atomic(const float* __restrict__ feats,
                           const float* __restrict__ weight,
                           const int* __restrict__ in_idx,
                           const int* __restrict__ out_idx,
                           const int* __restrict__ k_idx,
                           float* __restrict__ out,
                           int M) {
    long long t = (long long)blockIdx.x * blockDim.x + threadIdx.x;
    int m = (int)(t >> 4);
    int c = (int)(t & 15);
    if (m >= M) return;
    float f = feats[in_idx[m]];
    float w = weight[k_idx[m] * 16 + c];
    atomicAdd(out + (long long)out_idx[m] * 16 + c, f * w);
}

extern "C" void kernel_launch(void* const* d_in, const int* in_sizes, int n_in,
                              void* d_out, int out_size, void* d_ws, size_t ws_size,
                              hipStream_t stream) {
    const float* feats  = (const float*)d_in[0];
    const float* weight = (const float*)d_in[1];
    const int*   in_idx = (const int*)d_in[2];
    const int*   out_idx= (const int*)d_in[3];
    const int*   k_idx  = (const int*)d_in[4];
    float*       out    = (float*)d_out;

    const int M     = in_sizes[2];        // rulebook length
    const int n_out = out_size / 16;      // out_size in FLOATS; rows of 16 f32
    const int np    = (n_out + 1) & ~1;   // even stride for u32-pair reads

    const size_t need = (size_t)8 * (size_t)np * sizeof(unsigned short); // ~31 MB
    const int block = 256;

    if (d_ws != nullptr && ws_size >= need) {
        unsigned short* g = (unsigned short*)d_ws;
        hipMemsetAsync(g, 0, need, stream);   // bf16 +0 == 0x0000

        const int grid1 = (M + block - 1) / block;
        scatter_dense<<<grid1, block, 0, stream>>>(feats, in_idx, out_idx,
                                                   k_idx, g, M, np);

        const int nthr = (n_out + 1) / 2;
        const int grid2 = (nthr + block - 1) / block;
        reduce8<<<grid2, block, 0, stream>>>((const unsigned int*)g, weight,
                                             out, n_out, np / 2);

        sparse_add<<<grid1, block, 0, stream>>>(feats, weight, in_idx,
                                                out_idx, k_idx, out, M);
    } else {
        // d_out poisoned before every timed launch — zero it (out_size floats).
        hipMemsetAsync(d_out, 0, (size_t)out_size * sizeof(float), stream);
        const long long total = (long long)M * 16;
        const long long grid = (total + block - 1) / block;
        sparse_conv_scatter_atomic<<<(int)grid, block, 0, stream>>>(
            feats, weight, in_idx, out_idx, k_idx, out, M);
    }
}

// Round 7
// 278.054 us; speedup vs baseline: 1.8218x; 1.8218x over previous
//
#include <hip/hip_runtime.h>

// Sparse 3D conv (Cin=1, Cout=16), stride-2 — parity-split two-pass + compacted
// channel-parallel sparse atomics.
//
// Geometry: with stride 2, offsets d in {0,1}^3 (8 "dense" planes) carry exactly
// one entry per input (~88% of M), per-(o,k) unique => plain bf16 stores into
// g[8][np]. The 19 offsets with a -1 component (~12% of M) are coincidence hits.
//
//  pass 1: dense -> bf16 planes; sparse entry ids compacted via wave ballot
//  pass 2: out[o,:] = sum_p g[p][o] * W[k(p),:]  (overwrites every row)
//  pass 3: compacted sparse list, 16 LANES PER ENTRY (one 64B line per entry --
//          round 6 showed per-thread channel loops serialize atomics 64-way:
//          319us, 173MB writeback; channel-parallel baseline rate is ~12x faster)

typedef float vf4 __attribute__((ext_vector_type(4)));

__device__ inline unsigned short f32_to_bf16_rne(float x) {
    unsigned int u = __float_as_uint(x);
    unsigned int r = 0x7FFFu + ((u >> 16) & 1u);
    return (unsigned short)((u + r) >> 16);
}

// k = (dx+1)*9 + (dy+1)*3 + (dz+1). Dense iff all digits nonzero (d in {0,1}).
__device__ inline int dense_plane(int k) {   // -1 if sparse
    int a = k / 9, b = (k / 3) % 3, c = k % 3;
    if (a == 0 || b == 0 || c == 0) return -1;
    return ((a - 1) << 2) | ((b - 1) << 1) | (c - 1);
}

__global__ void __launch_bounds__(256)
scatter_dense(const float* __restrict__ feats,
              const int* __restrict__ in_idx,
              const int* __restrict__ out_idx,
              const int* __restrict__ k_idx,
              unsigned short* __restrict__ g,
              int* __restrict__ slist,
              int* __restrict__ scount,
              int M, int np) {
    int m = blockIdx.x * blockDim.x + threadIdx.x;
    bool sparse = false;
    if (m < M) {
        int k = k_idx[m];
        int p = dense_plane(k);
        if (p >= 0) {
            // (o,k) unique => plain store
            g[(size_t)p * np + out_idx[m]] = f32_to_bf16_rne(feats[in_idx[m]]);
        } else {
            sparse = true;
        }
    }
    // wave-aggregated compaction of sparse entry ids
    unsigned long long mask = __ballot(sparse);
    if (mask) {
        int lane = threadIdx.x & 63;
        int leader = __ffsll((long long)mask) - 1;
        int base = 0;
        if (lane == leader)
            base = atomicAdd(scount, __popcll(mask));
        base = __shfl(base, leader);
        if (sparse) {
            int pos = base + __popcll(mask & ((1ull << lane) - 1ull));
            slist[pos] = m;
        }
    }
}

__global__ void __launch_bounds__(256, 4)
reduce8(const unsigned int* __restrict__ g32,  // 8 planes as u32 (2x bf16)
        const float* __restrict__ weight,      // [27][16] f32
        float* __restrict__ out,
        int n_out, int half_np) {
    int t = blockIdx.x * blockDim.x + threadIdx.x;
    int o0 = t * 2;
    if (o0 >= n_out) return;

    unsigned int gu[8];
    #pragma unroll
    for (int p = 0; p < 8; ++p)
        gu[p] = g32[(size_t)p * half_np + t];   // coalesced per plane

    vf4 a0 = {0,0,0,0}, a1 = a0, a2 = a0, a3 = a0;
    vf4 b0 = a0, b1 = a0, b2 = a0, b3 = a0;
    const int KP[8] = {13, 14, 16, 17, 22, 23, 25, 26};
    #pragma unroll
    for (int p = 0; p < 8; ++p) {
        const vf4* w = (const vf4*)&weight[KP[p] * 16];  // wave-uniform -> SGPR
        vf4 w0 = w[0], w1 = w[1], w2 = w[2], w3 = w[3];
        float fa = __uint_as_float(gu[p] << 16);
        float fb = __uint_as_float(gu[p] & 0xFFFF0000u);
        a0 += fa * w0; a1 += fa * w1; a2 += fa * w2; a3 += fa * w3;
        b0 += fb * w0; b1 += fb * w1; b2 += fb * w2; b3 += fb * w3;
    }

    vf4* op = (vf4*)(out + (size_t)o0 * 16);
    op[0] = a0; op[1] = a1; op[2] = a2; op[3] = a3;   // coalesced 64B
    if (o0 + 1 < n_out) {
        op[4] = b0; op[5] = b1; op[6] = b2; op[7] = b3;
    }
}

__global__ void __launch_bounds__(256)
sparse_list_add(const float* __restrict__ feats,
                const float* __restrict__ weight,
                const int* __restrict__ in_idx,
                const int* __restrict__ out_idx,
                const int* __restrict__ k_idx,
                const int* __restrict__ slist,
                const int* __restrict__ scount,
                float* __restrict__ out) {
    const long long total = (long long)(*scount) * 16;
    const long long stride = (long long)gridDim.x * blockDim.x;
    for (long long t = (long long)blockIdx.x * blockDim.x + threadIdx.x;
         t < total; t += stride) {
        int e = (int)(t >> 4);
        int c = (int)(t & 15);          // 16 consecutive lanes = one 64B line
        int m = slist[e];
        float f = feats[in_idx[m]];
        float w = weight[k_idx[m] * 16 + c];
        atomicAdd(out + (long long)out_idx[m] * 16 + c, f * w);  // exact f32
    }
}

// ---- fallback path (ws too small): known-correct atomic scatter ----
__global__ void __launch_bounds__(256)
sparse_conv_scatter_atomic(const float* __restrict__ feats,
                           const float* __restrict__ weight,
                           const int* __restrict__ in_idx,
                           const int* __restrict__ out_idx,
                           const int* __restrict__ k_idx,
                           float* __restrict__ out,
                           int M) {
    long long t = (long long)blockIdx.x * blockDim.x + threadIdx.x;
    int m = (int)(t >> 4);
    int c = (int)(t & 15);
    if (m >= M) return;
    float f = feats[in_idx[m]];
    float w = weight[k_idx[m] * 16 + c];
    atomicAdd(out + (long long)out_idx[m] * 16 + c, f * w);
}

extern "C" void kernel_launch(void* const* d_in, const int* in_sizes, int n_in,
                              void* d_out, int out_size, void* d_ws, size_t ws_size,
                              hipStream_t stream) {
    const float* feats  = (const float*)d_in[0];
    const float* weight = (const float*)d_in[1];
    const int*   in_idx = (const int*)d_in[2];
    const int*   out_idx= (const int*)d_in[3];
    const int*   k_idx  = (const int*)d_in[4];
    float*       out    = (float*)d_out;

    const int M     = in_sizes[2];        // rulebook length
    const int n_out = out_size / 16;      // out_size in FLOATS; rows of 16 f32
    const int np    = (n_out + 1) & ~1;   // even stride for u32-pair reads

    const size_t planes_bytes = (size_t)8 * (size_t)np * sizeof(unsigned short); // ~31 MB
    const size_t scount_off   = (planes_bytes + 255) & ~(size_t)255;
    const size_t slist_off    = scount_off + 256;
    const size_t need = slist_off + (size_t)M * sizeof(int);
    const int block = 256;

    if (d_ws != nullptr && ws_size >= need) {
        unsigned short* g = (unsigned short*)d_ws;
        int* scount = (int*)((char*)d_ws + scount_off);
        int* slist  = (int*)((char*)d_ws + slist_off);

        hipMemsetAsync(g, 0, planes_bytes, stream);   // bf16 +0 == 0x0000
        hipMemsetAsync(scount, 0, sizeof(int), stream);

        const int grid1 = (M + block - 1) / block;
        scatter_dense<<<grid1, block, 0, stream>>>(feats, in_idx, out_idx,
                                                   k_idx, g, slist, scount,
                                                   M, np);

        const int nthr = (n_out + 1) / 2;
        const int grid2 = (nthr + block - 1) / block;
        reduce8<<<grid2, block, 0, stream>>>((const unsigned int*)g, weight,
                                             out, n_out, np / 2);

        sparse_list_add<<<2048, block, 0, stream>>>(feats, weight, in_idx,
                                                    out_idx, k_idx, slist,
                                                    scount, out);
    } else {
        // d_out poisoned before every timed launch — zero it (out_size floats).
        hipMemsetAsync(d_out, 0, (size_t)out_size * sizeof(float), stream);
        const long long total = (long long)M * 16;
        const long long grid = (total + block - 1) / block;
        sparse_conv_scatter_atomic<<<(int)grid, block, 0, stream>>>(
            feats, weight, in_idx, out_idx, k_idx, out, M);
    }
}

// Round 8
// 260.029 us; speedup vs baseline: 1.9480x; 1.0693x over previous
//
#include <hip/hip_runtime.h>

// Sparse 3D conv (Cin=1, Cout=16), stride-2 — parity-split two-pass +
// full-rescan channel-parallel sparse atomics. NO compaction.
//
// Geometry: offsets d in {0,1}^3 (8 dense planes) carry one entry per input
// (~88% of M), per-(o,k) unique => plain bf16 stores into g[8][np].
// The 19 offsets with a -1 component (~12% of M) are coincidence hits.
//
// Round-7 lesson: wave-ballot compaction onto ONE global counter serialized
// scatter_dense at ~2ns/atomic (72.6us, 0.76 TB/s, VALUBusy 3.4%). Removed.
// Round-6 lesson: sparse atomics must be 16-lanes-per-entry (one 64B line),
// not 16-channels-per-thread (64 lines per wave instruction).
//
//  pass 1: dense -> bf16 planes (pure stores)
//  pass 2: out[o,:] = sum_p g[p][o] * W[k(p),:]  (overwrites every row)
//  pass 3: rescan rulebook M*16 threads; dense groups early-out; sparse
//          entries do 16 coalesced f32 atomicAdds (exact).

typedef float vf4 __attribute__((ext_vector_type(4)));

__device__ inline unsigned short f32_to_bf16_rne(float x) {
    unsigned int u = __float_as_uint(x);
    unsigned int r = 0x7FFFu + ((u >> 16) & 1u);
    return (unsigned short)((u + r) >> 16);
}

// k = (dx+1)*9 + (dy+1)*3 + (dz+1). Dense iff all digits nonzero (d in {0,1}).
__device__ inline int dense_plane(int k) {   // -1 if sparse
    int a = k / 9, b = (k / 3) % 3, c = k % 3;
    if (a == 0 || b == 0 || c == 0) return -1;
    return ((a - 1) << 2) | ((b - 1) << 1) | (c - 1);
}

__global__ void __launch_bounds__(256)
scatter_dense(const float* __restrict__ feats,
              const int* __restrict__ in_idx,
              const int* __restrict__ out_idx,
              const int* __restrict__ k_idx,
              unsigned short* __restrict__ g,
              int M, int np) {
    int m = blockIdx.x * blockDim.x + threadIdx.x;
    if (m >= M) return;
    int p = dense_plane(k_idx[m]);
    if (p < 0) return;                       // sparse -> pass 3
    // (o,k) unique => plain store
    g[(size_t)p * np + out_idx[m]] = f32_to_bf16_rne(feats[in_idx[m]]);
}

__global__ void __launch_bounds__(256, 4)
reduce8(const unsigned int* __restrict__ g32,  // 8 planes as u32 (2x bf16)
        const float* __restrict__ weight,      // [27][16] f32
        float* __restrict__ out,
        int n_out, int half_np) {
    int t = blockIdx.x * blockDim.x + threadIdx.x;
    int o0 = t * 2;
    if (o0 >= n_out) return;

    unsigned int gu[8];
    #pragma unroll
    for (int p = 0; p < 8; ++p)
        gu[p] = g32[(size_t)p * half_np + t];   // coalesced per plane

    vf4 a0 = {0,0,0,0}, a1 = a0, a2 = a0, a3 = a0;
    vf4 b0 = a0, b1 = a0, b2 = a0, b3 = a0;
    const int KP[8] = {13, 14, 16, 17, 22, 23, 25, 26};
    #pragma unroll
    for (int p = 0; p < 8; ++p) {
        const vf4* w = (const vf4*)&weight[KP[p] * 16];  // wave-uniform -> SGPR
        vf4 w0 = w[0], w1 = w[1], w2 = w[2], w3 = w[3];
        float fa = __uint_as_float(gu[p] << 16);
        float fb = __uint_as_float(gu[p] & 0xFFFF0000u);
        a0 += fa * w0; a1 += fa * w1; a2 += fa * w2; a3 += fa * w3;
        b0 += fb * w0; b1 += fb * w1; b2 += fb * w2; b3 += fb * w3;
    }

    vf4* op = (vf4*)(out + (size_t)o0 * 16);
    op[0] = a0; op[1] = a1; op[2] = a2; op[3] = a3;   // coalesced 64B
    if (o0 + 1 < n_out) {
        op[4] = b0; op[5] = b1; op[6] = b2; op[7] = b3;
    }
}

__global__ void __launch_bounds__(256)
sparse_scan_add(const float* __restrict__ feats,
                const float* __restrict__ weight,
                const int* __restrict__ in_idx,
                const int* __restrict__ out_idx,
                const int* __restrict__ k_idx,
                float* __restrict__ out,
                int M) {
    long long t = (long long)blockIdx.x * blockDim.x + threadIdx.x;
    int m = (int)(t >> 4);
    int c = (int)(t & 15);               // 16 consecutive lanes = one 64B line
    if (m >= M) return;
    int k = k_idx[m];                    // broadcast within the 16-lane group
    if (dense_plane(k) >= 0) return;     // 88% of groups exit here
    float f = feats[in_idx[m]];
    float w = weight[k * 16 + c];
    atomicAdd(out + (long long)out_idx[m] * 16 + c, f * w);  // exact f32
}

// ---- fallback path (ws too small): known-correct atomic scatter ----
__global__ void __launch_bounds__(256)
sparse_conv_scatter_atomic(const float* __restrict__ feats,
                           const float* __restrict__ weight,
                           const int* __restrict__ in_idx,
                           const int* __restrict__ out_idx,
                           const int* __restrict__ k_idx,
                           float* __restrict__ out,
                           int M) {
    long long t = (long long)blockIdx.x * blockDim.x + threadIdx.x;
    int m = (int)(t >> 4);
    int c = (int)(t & 15);
    if (m >= M) return;
    float f = feats[in_idx[m]];
    float w = weight[k_idx[m] * 16 + c];
    atomicAdd(out + (long long)out_idx[m] * 16 + c, f * w);
}

extern "C" void kernel_launch(void* const* d_in, const int* in_sizes, int n_in,
                              void* d_out, int out_size, void* d_ws, size_t ws_size,
                              hipStream_t stream) {
    const float* feats  = (const float*)d_in[0];
    const float* weight = (const float*)d_in[1];
    const int*   in_idx = (const int*)d_in[2];
    const int*   out_idx= (const int*)d_in[3];
    const int*   k_idx  = (const int*)d_in[4];
    float*       out    = (float*)d_out;

    const int M     = in_sizes[2];        // rulebook length
    const int n_out = out_size / 16;      // out_size in FLOATS; rows of 16 f32
    const int np    = (n_out + 1) & ~1;   // even stride for u32-pair reads

    const size_t need = (size_t)8 * (size_t)np * sizeof(unsigned short); // ~31 MB
    const int block = 256;

    if (d_ws != nullptr && ws_size >= need) {
        unsigned short* g = (unsigned short*)d_ws;
        hipMemsetAsync(g, 0, need, stream);   // bf16 +0 == 0x0000

        const int grid1 = (M + block - 1) / block;
        scatter_dense<<<grid1, block, 0, stream>>>(feats, in_idx, out_idx,
                                                   k_idx, g, M, np);

        const int nthr = (n_out + 1) / 2;
        const int grid2 = (nthr + block - 1) / block;
        reduce8<<<grid2, block, 0, stream>>>((const unsigned int*)g, weight,
                                             out, n_out, np / 2);

        const long long total3 = (long long)M * 16;
        const int grid3 = (int)((total3 + block - 1) / block);
        sparse_scan_add<<<grid3, block, 0, stream>>>(feats, weight, in_idx,
                                                     out_idx, k_idx, out, M);
    } else {
        // d_out poisoned before every timed launch — zero it (out_size floats).
        hipMemsetAsync(d_out, 0, (size_t)out_size * sizeof(float), stream);
        const long long total = (long long)M * 16;
        const long long grid = (total + block - 1) / block;
        sparse_conv_scatter_atomic<<<(int)grid, block, 0, stream>>>(
            feats, weight, in_idx, out_idx, k_idx, out, M);
    }
}

// Round 9
// 242.973 us; speedup vs baseline: 2.0848x; 1.0702x over previous
//
#include <hip/hip_runtime.h>

// Sparse 3D conv (Cin=1, Cout=16), stride-2 — parity-split two-pass +
// full-rescan sparse atomics, with 4-entry-per-thread ILP.
//
// Geometry: offsets d in {0,1}^3 (8 dense planes) carry one entry per input
// (~88% of M), per-(o,k) unique => plain bf16 stores into g[8][np].
// The 19 offsets with a -1 component (~12% of M) are coincidence hits.
//
// Round-8 lesson: scatter was LATENCY-bound (occ 77%, VALU 3.4%, 0.76 TB/s):
// one serial idx->gather->store chain per thread. Fix: 4 independent entries
// per thread (4 gathers in flight) + int4-vectorized index loads.
// Round-7 lesson: no global compaction counters (2ns/atomic serialization).
// Round-6 lesson: sparse atomics 16-lanes-per-entry (one 64B line), never
// per-thread channel loops.

typedef float vf4 __attribute__((ext_vector_type(4)));
typedef int   vi4 __attribute__((ext_vector_type(4)));

__device__ inline unsigned short f32_to_bf16_rne(float x) {
    unsigned int u = __float_as_uint(x);
    unsigned int r = 0x7FFFu + ((u >> 16) & 1u);
    return (unsigned short)((u + r) >> 16);
}

// k = (dx+1)*9 + (dy+1)*3 + (dz+1). Dense iff all digits nonzero (d in {0,1}).
__device__ inline int dense_plane(int k) {   // -1 if sparse
    int a = k / 9, b = (k / 3) % 3, c = k % 3;
    if (a == 0 || b == 0 || c == 0) return -1;
    return ((a - 1) << 2) | ((b - 1) << 1) | (c - 1);
}

__global__ void __launch_bounds__(256)
scatter_dense4(const float* __restrict__ feats,
               const int* __restrict__ in_idx,
               const int* __restrict__ out_idx,
               const int* __restrict__ k_idx,
               unsigned short* __restrict__ g,
               int M, int np) {
    int t = blockIdx.x * blockDim.x + threadIdx.x;
    int base = t * 4;
    if (base + 3 < M) {
        vi4 kk = *(const vi4*)&k_idx[base];    // 16B coalesced
        vi4 ii = *(const vi4*)&in_idx[base];
        vi4 oo = *(const vi4*)&out_idx[base];
        int p0 = dense_plane(kk.x), p1 = dense_plane(kk.y),
            p2 = dense_plane(kk.z), p3 = dense_plane(kk.w);
        // 4 independent random gathers in flight
        float f0 = feats[ii.x], f1 = feats[ii.y],
              f2 = feats[ii.z], f3 = feats[ii.w];
        if (p0 >= 0) g[(size_t)p0 * np + oo.x] = f32_to_bf16_rne(f0);
        if (p1 >= 0) g[(size_t)p1 * np + oo.y] = f32_to_bf16_rne(f1);
        if (p2 >= 0) g[(size_t)p2 * np + oo.z] = f32_to_bf16_rne(f2);
        if (p3 >= 0) g[(size_t)p3 * np + oo.w] = f32_to_bf16_rne(f3);
    } else if (base < M) {
        for (int m = base; m < M; ++m) {
            int p = dense_plane(k_idx[m]);
            if (p >= 0)
                g[(size_t)p * np + out_idx[m]] =
                    f32_to_bf16_rne(feats[in_idx[m]]);
        }
    }
}

__global__ void __launch_bounds__(256, 4)
reduce8(const unsigned int* __restrict__ g32,  // 8 planes as u32 (2x bf16)
        const float* __restrict__ weight,      // [27][16] f32
        float* __restrict__ out,
        int n_out, int half_np) {
    int t = blockIdx.x * blockDim.x + threadIdx.x;
    int o0 = t * 2;
    if (o0 >= n_out) return;

    unsigned int gu[8];
    #pragma unroll
    for (int p = 0; p < 8; ++p)
        gu[p] = g32[(size_t)p * half_np + t];   // 8 independent streams

    vf4 a0 = {0,0,0,0}, a1 = a0, a2 = a0, a3 = a0;
    vf4 b0 = a0, b1 = a0, b2 = a0, b3 = a0;
    const int KP[8] = {13, 14, 16, 17, 22, 23, 25, 26};
    #pragma unroll
    for (int p = 0; p < 8; ++p) {
        const vf4* w = (const vf4*)&weight[KP[p] * 16];  // wave-uniform -> SGPR
        vf4 w0 = w[0], w1 = w[1], w2 = w[2], w3 = w[3];
        float fa = __uint_as_float(gu[p] << 16);
        float fb = __uint_as_float(gu[p] & 0xFFFF0000u);
        a0 += fa * w0; a1 += fa * w1; a2 += fa * w2; a3 += fa * w3;
        b0 += fb * w0; b1 += fb * w1; b2 += fb * w2; b3 += fb * w3;
    }

    vf4* op = (vf4*)(out + (size_t)o0 * 16);
    op[0] = a0; op[1] = a1; op[2] = a2; op[3] = a3;   // coalesced 64B
    if (o0 + 1 < n_out) {
        op[4] = b0; op[5] = b1; op[6] = b2; op[7] = b3;
    }
}

__global__ void __launch_bounds__(256)
sparse_scan_add4(const float* __restrict__ feats,
                 const float* __restrict__ weight,
                 const int* __restrict__ in_idx,
                 const int* __restrict__ out_idx,
                 const int* __restrict__ k_idx,
                 float* __restrict__ out,
                 int M) {
    long long t = (long long)blockIdx.x * blockDim.x + threadIdx.x;
    int grp = (int)(t >> 4);            // each 16-lane group: 4 entries
    int c   = (int)(t & 15);            // 16 consecutive lanes = one 64B line
    int base = grp * 4;
    if (base >= M) return;
    if (base + 3 < M) {
        vi4 kk = *(const vi4*)&k_idx[base];   // one line for the whole group
        int p0 = dense_plane(kk.x), p1 = dense_plane(kk.y),
            p2 = dense_plane(kk.z), p3 = dense_plane(kk.w);
        if ((p0 | p1 | p2 | p3) >= 0) return;  // all 4 dense (-1 ORs to -1)
        vi4 ii = *(const vi4*)&in_idx[base];
        vi4 oo = *(const vi4*)&out_idx[base];
        if (p0 < 0) {
            float f = feats[ii.x];
            atomicAdd(out + (long long)oo.x * 16 + c, f * weight[kk.x * 16 + c]);
        }
        if (p1 < 0) {
            float f = feats[ii.y];
            atomicAdd(out + (long long)oo.y * 16 + c, f * weight[kk.y * 16 + c]);
        }
        if (p2 < 0) {
            float f = feats[ii.z];
            atomicAdd(out + (long long)oo.z * 16 + c, f * weight[kk.z * 16 + c]);
        }
        if (p3 < 0) {
            float f = feats[ii.w];
            atomicAdd(out + (long long)oo.w * 16 + c, f * weight[kk.w * 16 + c]);
        }
    } else {
        for (int m = base; m < M; ++m) {
            int k = k_idx[m];
            if (dense_plane(k) >= 0) continue;
            float f = feats[in_idx[m]];
            atomicAdd(out + (long long)out_idx[m] * 16 + c,
                      f * weight[k * 16 + c]);
        }
    }
}

// ---- fallback path (ws too small): known-correct atomic scatter ----
__global__ void __launch_bounds__(256)
sparse_conv_scatter_atomic(const float* __restrict__ feats,
                           const float* __restrict__ weight,
                           const int* __restrict__ in_idx,
                           const int* __restrict__ out_idx,
                           const int* __restrict__ k_idx,
                           float* __restrict__ out,
                           int M) {
    long long t = (long long)blockIdx.x * blockDim.x + threadIdx.x;
    int m = (int)(t >> 4);
    int c = (int)(t & 15);
    if (m >= M) return;
    float f = feats[in_idx[m]];
    float w = weight[k_idx[m] * 16 + c];
    atomicAdd(out + (long long)out_idx[m] * 16 + c, f * w);
}

extern "C" void kernel_launch(void* const* d_in, const int* in_sizes, int n_in,
                              void* d_out, int out_size, void* d_ws, size_t ws_size,
                              hipStream_t stream) {
    const float* feats  = (const float*)d_in[0];
    const float* weight = (const float*)d_in[1];
    const int*   in_idx = (const int*)d_in[2];
    const int*   out_idx= (const int*)d_in[3];
    const int*   k_idx  = (const int*)d_in[4];
    float*       out    = (float*)d_out;

    const int M     = in_sizes[2];        // rulebook length
    const int n_out = out_size / 16;      // out_size in FLOATS; rows of 16 f32
    const int np    = (n_out + 1) & ~1;   // even stride for u32-pair reads

    const size_t need = (size_t)8 * (size_t)np * sizeof(unsigned short); // ~31 MB
    const int block = 256;

    if (d_ws != nullptr && ws_size >= need) {
        unsigned short* g = (unsigned short*)d_ws;
        hipMemsetAsync(g, 0, need, stream);   // bf16 +0 == 0x0000

        const int nthr1 = (M + 3) / 4;
        const int grid1 = (nthr1 + block - 1) / block;
        scatter_dense4<<<grid1, block, 0, stream>>>(feats, in_idx, out_idx,
                                                    k_idx, g, M, np);

        const int nthr2 = (n_out + 1) / 2;
        const int grid2 = (nthr2 + block - 1) / block;
        reduce8<<<grid2, block, 0, stream>>>((const unsigned int*)g, weight,
                                             out, n_out, np / 2);

        const long long nthr3 = (long long)((M + 3) / 4) * 16;
        const int grid3 = (int)((nthr3 + block - 1) / block);
        sparse_scan_add4<<<grid3, block, 0, stream>>>(feats, weight, in_idx,
                                                      out_idx, k_idx, out, M);
    } else {
        // d_out poisoned before every timed launch — zero it (out_size floats).
        hipMemsetAsync(d_out, 0, (size_t)out_size * sizeof(float), stream);
        const long long total = (long long)M * 16;
        const long long grid = (total + block - 1) / block;
        sparse_conv_scatter_atomic<<<(int)grid, block, 0, stream>>>(
            feats, weight, in_idx, out_idx, k_idx, out, M);
    }
}